// Round 4
// baseline (268.383 us; speedup 1.0000x reference)
//
#include <hip/hip_runtime.h>
#include <cmath>

// GraphSAGE forward for MI355X (gfx950).
// R4: fused pipeline — K1: gemm; K2: gather+relu+gemm; K3: gather+relu+gemm+gemm+logsoftmax.
// CSR build: XCD-partitioned (src-range per XCD), u16 col.

#define SCAN_BS 512
#define NXCD 8

// --- Partitioned degree count: group g handles src in [g*chunk, (g+1)*chunk) ---
__global__ __launch_bounds__(256) void count_deg_part(const int* __restrict__ src,
                                                      int* __restrict__ deg, int E, int N) {
    int g    = blockIdx.x & (NXCD - 1);
    int bpg  = blockIdx.x >> 3;
    int nbpg = gridDim.x >> 3;
    int chunk = (N + NXCD - 1) / NXCD;
    int lo = g * chunk;
    int hi = min(N, lo + chunk);
    for (int e = bpg * 256 + threadIdx.x; e < E; e += nbpg * 256) {
        int s = src[e];
        if (s >= lo && s < hi) atomicAdd(&deg[s], 1);
    }
}

// --- 3-phase exclusive scan of deg[N] -> rowptr[N+1] (+ cursor copy) ---
__global__ __launch_bounds__(SCAN_BS) void scan1_kernel(const int* __restrict__ deg,
                                                        int* __restrict__ chunkScan,
                                                        int* __restrict__ blockSums, int N) {
    __shared__ int tmp[SCAN_BS];
    int gid = blockIdx.x * SCAN_BS + threadIdx.x;
    int v = (gid < N) ? deg[gid] : 0;
    tmp[threadIdx.x] = v;
    __syncthreads();
    for (int off = 1; off < SCAN_BS; off <<= 1) {
        int add = (threadIdx.x >= off) ? tmp[threadIdx.x - off] : 0;
        __syncthreads();
        tmp[threadIdx.x] += add;
        __syncthreads();
    }
    if (gid < N) chunkScan[gid] = tmp[threadIdx.x] - v;
    if (threadIdx.x == SCAN_BS - 1) blockSums[blockIdx.x] = tmp[threadIdx.x];
}

__global__ __launch_bounds__(SCAN_BS) void scan2_kernel(int* __restrict__ blockSums, int nb) {
    __shared__ int tmp[SCAN_BS];
    int v = (threadIdx.x < nb) ? blockSums[threadIdx.x] : 0;
    tmp[threadIdx.x] = v;
    __syncthreads();
    for (int off = 1; off < SCAN_BS; off <<= 1) {
        int add = (threadIdx.x >= off) ? tmp[threadIdx.x - off] : 0;
        __syncthreads();
        tmp[threadIdx.x] += add;
        __syncthreads();
    }
    if (threadIdx.x < nb) blockSums[threadIdx.x] = tmp[threadIdx.x] - v;
}

__global__ void scan3_kernel(const int* __restrict__ chunkScan, const int* __restrict__ blockSums,
                             int* __restrict__ rowptr, int* __restrict__ cursor, int N, int E) {
    int gid = blockIdx.x * blockDim.x + threadIdx.x;
    if (gid < N) {
        int v = chunkScan[gid] + blockSums[gid / SCAN_BS];
        rowptr[gid] = v;
        cursor[gid] = v;
    }
    if (gid == 0) rowptr[N] = E;
}

// --- Partitioned CSR column fill (u16) ---
__global__ __launch_bounds__(256) void build_col_part(const int* __restrict__ src,
                                                      const int* __restrict__ dst,
                                                      int* __restrict__ cursor,
                                                      unsigned short* __restrict__ col,
                                                      int E, int N) {
    int g    = blockIdx.x & (NXCD - 1);
    int bpg  = blockIdx.x >> 3;
    int nbpg = gridDim.x >> 3;
    int chunk = (N + NXCD - 1) / NXCD;
    int lo = g * chunk;
    int hi = min(N, lo + chunk);
    for (int e = bpg * 256 + threadIdx.x; e < E; e += nbpg * 256) {
        int s = src[e];
        if (s >= lo && s < hi) {
            int pos = atomicAdd(&cursor[s], 1);
            col[pos] = (unsigned short)dst[e];
        }
    }
}

// Gather-mean of node `node` into acc (lane = feature dim). Returns mean value.
__device__ __forceinline__ float gather_row(const float* __restrict__ H,
                                            const int* __restrict__ rowptr,
                                            const unsigned short* __restrict__ col,
                                            int node, int lane) {
    int beg = rowptr[node];
    int end = rowptr[node + 1];
    float acc = 0.f;
    int e = beg;
    for (; e + 4 <= end; e += 4) {
        int t0 = col[e], t1 = col[e + 1], t2 = col[e + 2], t3 = col[e + 3];
        float v0 = H[(size_t)t0 * 64 + lane];
        float v1 = H[(size_t)t1 * 64 + lane];
        float v2 = H[(size_t)t2 * 64 + lane];
        float v3 = H[(size_t)t3 * 64 + lane];
        acc += (v0 + v1) + (v2 + v3);
    }
    for (; e < end; ++e) acc += H[(size_t)col[e] * 64 + lane];
    float inv = (end > beg) ? 1.f / (float)(end - beg) : 0.f;
    return acc * inv;
}

// K1: Y[n x 64] = X[n x 64] @ W + b. 256 thr, 32 rows/block, W column in VGPRs.
__global__ __launch_bounds__(256) void gemm_fast(const float* __restrict__ X,
                                                 const float* __restrict__ W,
                                                 const float* __restrict__ b,
                                                 float* __restrict__ Y, int n) {
    __shared__ float xs[32][64];
    const int tid  = threadIdx.x;
    const int lane = tid & 63;
    const int wv   = tid >> 6;
    const int row0 = blockIdx.x * 32;

    for (int i = tid; i < 32 * 64; i += 256) {
        int rr = row0 + (i >> 6);
        xs[i >> 6][i & 63] = (rr < n) ? X[(size_t)row0 * 64 + i] : 0.f;
    }
    float w[64];
#pragma unroll
    for (int k = 0; k < 64; ++k) w[k] = W[k * 64 + lane];
    const float bias = b[lane];
    __syncthreads();

#pragma unroll
    for (int r8 = 0; r8 < 8; ++r8) {
        const int r = wv * 8 + r8;
        float a0 = 0.f, a1 = 0.f, a2 = 0.f, a3 = 0.f;
#pragma unroll
        for (int k4 = 0; k4 < 16; ++k4) {
            float4 xv = *(const float4*)&xs[r][k4 * 4];
            a0 = fmaf(xv.x, w[4 * k4 + 0], a0);
            a1 = fmaf(xv.y, w[4 * k4 + 1], a1);
            a2 = fmaf(xv.z, w[4 * k4 + 2], a2);
            a3 = fmaf(xv.w, w[4 * k4 + 3], a3);
        }
        const int grow = row0 + r;
        if (grow < n) Y[(size_t)grow * 64 + lane] = bias + ((a0 + a1) + (a2 + a3));
    }
}

// K2: H2[node] = relu(gather_mean(H1)[node]) @ W + b, fused per 32-node block.
__global__ __launch_bounds__(256) void fused_gather_gemm(const float* __restrict__ H,
                                                         const int* __restrict__ rowptr,
                                                         const unsigned short* __restrict__ col,
                                                         const float* __restrict__ W,
                                                         const float* __restrict__ b,
                                                         float* __restrict__ Y, int n) {
    __shared__ float xs[32][64];
    const int tid  = threadIdx.x;
    const int lane = tid & 63;
    const int wv   = tid >> 6;
    const int row0 = blockIdx.x * 32;

    float w[64];
#pragma unroll
    for (int k = 0; k < 64; ++k) w[k] = W[k * 64 + lane];
    const float bias = b[lane];

    // Gather phase: each wave computes 8 node rows into LDS (relu applied).
#pragma unroll
    for (int r8 = 0; r8 < 8; ++r8) {
        const int r = wv * 8 + r8;
        const int node = row0 + r;
        float v = (node < n) ? gather_row(H, rowptr, col, node, lane) : 0.f;
        xs[r][lane] = fmaxf(v, 0.f);
    }
    __syncthreads();

#pragma unroll
    for (int r8 = 0; r8 < 8; ++r8) {
        const int r = wv * 8 + r8;
        float a0 = 0.f, a1 = 0.f, a2 = 0.f, a3 = 0.f;
#pragma unroll
        for (int k4 = 0; k4 < 16; ++k4) {
            float4 xv = *(const float4*)&xs[r][k4 * 4];
            a0 = fmaf(xv.x, w[4 * k4 + 0], a0);
            a1 = fmaf(xv.y, w[4 * k4 + 1], a1);
            a2 = fmaf(xv.z, w[4 * k4 + 2], a2);
            a3 = fmaf(xv.w, w[4 * k4 + 3], a3);
        }
        const int grow = row0 + r;
        if (grow < n) Y[(size_t)grow * 64 + lane] = bias + ((a0 + a1) + (a2 + a3));
    }
}

// K3: out[node] = log_softmax( (relu(gather_mean(H2)[node]) @ Wp1 + bp1) @ Wp2 + bp2 )
__global__ __launch_bounds__(256) void fused_gather_post(const float* __restrict__ H,
                                                         const int* __restrict__ rowptr,
                                                         const unsigned short* __restrict__ col,
                                                         const float* __restrict__ Wp1,
                                                         const float* __restrict__ bp1,
                                                         const float* __restrict__ Wp2,
                                                         const float* __restrict__ bp2,
                                                         float* __restrict__ out, int n) {
    __shared__ float xs[32][64];
    __shared__ float ys[32][64];
    const int tid  = threadIdx.x;
    const int lane = tid & 63;
    const int wv   = tid >> 6;
    const int row0 = blockIdx.x * 32;

    float w[64];
#pragma unroll
    for (int k = 0; k < 64; ++k) w[k] = Wp1[k * 64 + lane];
    const float bias1 = bp1[lane];

    // Gather phase (relu'd A2 rows into xs).
#pragma unroll
    for (int r8 = 0; r8 < 8; ++r8) {
        const int r = wv * 8 + r8;
        const int node = row0 + r;
        float v = (node < n) ? gather_row(H, rowptr, col, node, lane) : 0.f;
        xs[r][lane] = fmaxf(v, 0.f);
    }
    __syncthreads();

    // GEMM1: H3 rows into ys.
#pragma unroll
    for (int r8 = 0; r8 < 8; ++r8) {
        const int r = wv * 8 + r8;
        float a0 = 0.f, a1 = 0.f, a2 = 0.f, a3 = 0.f;
#pragma unroll
        for (int k4 = 0; k4 < 16; ++k4) {
            float4 xv = *(const float4*)&xs[r][k4 * 4];
            a0 = fmaf(xv.x, w[4 * k4 + 0], a0);
            a1 = fmaf(xv.y, w[4 * k4 + 1], a1);
            a2 = fmaf(xv.z, w[4 * k4 + 2], a2);
            a3 = fmaf(xv.w, w[4 * k4 + 3], a3);
        }
        ys[r][lane] = bias1 + ((a0 + a1) + (a2 + a3));
    }

    // Reload weights for GEMM2 (Wp2: 64 x 40).
    float w2[64];
#pragma unroll
    for (int k = 0; k < 64; ++k) w2[k] = (lane < 40) ? Wp2[k * 40 + lane] : 0.f;
    const float bias2 = (lane < 40) ? bp2[lane] : 0.f;
    __syncthreads();

    // GEMM2 + log_softmax per row.
#pragma unroll
    for (int r8 = 0; r8 < 8; ++r8) {
        const int r = wv * 8 + r8;
        float a0 = 0.f, a1 = 0.f, a2 = 0.f, a3 = 0.f;
#pragma unroll
        for (int k4 = 0; k4 < 16; ++k4) {
            float4 xv = *(const float4*)&ys[r][k4 * 4];
            a0 = fmaf(xv.x, w2[4 * k4 + 0], a0);
            a1 = fmaf(xv.y, w2[4 * k4 + 1], a1);
            a2 = fmaf(xv.z, w2[4 * k4 + 2], a2);
            a3 = fmaf(xv.w, w2[4 * k4 + 3], a3);
        }
        float v = bias2 + ((a0 + a1) + (a2 + a3));
        // Row log-softmax across lanes 0..39 (others padded).
        float vm = (lane < 40) ? v : -INFINITY;
        float m = vm;
#pragma unroll
        for (int o = 32; o; o >>= 1) m = fmaxf(m, __shfl_xor(m, o));
        float e = (lane < 40) ? expf(vm - m) : 0.f;
        float s = e;
#pragma unroll
        for (int o = 32; o; o >>= 1) s += __shfl_xor(s, o);
        float ls = logf(s);
        const int grow = row0 + r;
        if (grow < n && lane < 40) out[(size_t)grow * 40 + lane] = vm - m - ls;
    }
}

extern "C" void kernel_launch(void* const* d_in, const int* in_sizes, int n_in,
                              void* d_out, int out_size, void* d_ws, size_t ws_size,
                              hipStream_t stream) {
    const float* x   = (const float*)d_in[0];
    const int*   ei  = (const int*)d_in[1];
    const float* W1  = (const float*)d_in[2];
    const float* b1  = (const float*)d_in[3];
    const float* W2  = (const float*)d_in[4];
    const float* b2  = (const float*)d_in[5];
    const float* Wp1 = (const float*)d_in[6];
    const float* bp1 = (const float*)d_in[7];
    const float* Wp2 = (const float*)d_in[8];
    const float* bp2 = (const float*)d_in[9];
    float* out = (float*)d_out;

    const int N = in_sizes[0] / 64;
    const int E = in_sizes[1] / 2;
    const int* src = ei;        // edge_index[0, :]
    const int* dst = ei + E;    // edge_index[1, :]

    // Workspace layout
    char*  wsb = (char*)d_ws;
    size_t off = 0;
    auto alloc = [&](size_t bytes) { void* p = wsb + off; off += (bytes + 511) & ~(size_t)511; return p; };
    int*            deg       = (int*)alloc((size_t)N * 4);
    int*            rowptr    = (int*)alloc((size_t)(N + 1) * 4);
    int*            cursor    = (int*)alloc((size_t)N * 4);
    int*            chunkScan = (int*)alloc((size_t)N * 4);
    int*            blockSums = (int*)alloc((size_t)SCAN_BS * 4);
    unsigned short* col       = (unsigned short*)alloc((size_t)E * 2);
    float*          B1        = (float*)alloc((size_t)N * 64 * 4);
    float*          B2        = (float*)alloc((size_t)N * 64 * 4);
    (void)ws_size; (void)n_in; (void)out_size;

    const int scanBlocks = (N + SCAN_BS - 1) / SCAN_BS;
    const int nb32       = (N + 31) / 32;
    const int partBlocks = 1024;

    // --- Build CSR ---
    hipMemsetAsync(deg, 0, (size_t)N * 4, stream);
    count_deg_part<<<partBlocks, 256, 0, stream>>>(src, deg, E, N);
    scan1_kernel<<<scanBlocks, SCAN_BS, 0, stream>>>(deg, chunkScan, blockSums, N);
    scan2_kernel<<<1, SCAN_BS, 0, stream>>>(blockSums, scanBlocks);
    scan3_kernel<<<(N + 255) / 256, 256, 0, stream>>>(chunkScan, blockSums, rowptr, cursor, N, E);
    build_col_part<<<partBlocks, 256, 0, stream>>>(src, dst, cursor, col, E, N);

    // --- Fused pipeline ---
    gemm_fast<<<nb32, 256, 0, stream>>>(x, W1, b1, B1, N);                                   // H1
    fused_gather_gemm<<<nb32, 256, 0, stream>>>(B1, rowptr, col, W2, b2, B2, N);             // H2
    fused_gather_post<<<nb32, 256, 0, stream>>>(B2, rowptr, col, Wp1, bp1, Wp2, bp2, out, N);
}

// Round 5
// 231.072 us; speedup vs baseline: 1.1615x; 1.1615x over previous
//
#include <hip/hip_runtime.h>
#include <cmath>

// GraphSAGE forward for MI355X (gfx950).
// R5: gathers un-fused (latency-bound -> need max wave parallelism, R4 lesson);
//     compute-shaped fusion kept for post_mp; 8-deep gather unroll.

#define SCAN_BS 512
#define NXCD 8

// --- Partitioned degree count: group g handles src in [g*chunk, (g+1)*chunk) ---
__global__ __launch_bounds__(256) void count_deg_part(const int* __restrict__ src,
                                                      int* __restrict__ deg, int E, int N) {
    int g    = blockIdx.x & (NXCD - 1);
    int bpg  = blockIdx.x >> 3;
    int nbpg = gridDim.x >> 3;
    int chunk = (N + NXCD - 1) / NXCD;
    int lo = g * chunk;
    int hi = min(N, lo + chunk);
    for (int e = bpg * 256 + threadIdx.x; e < E; e += nbpg * 256) {
        int s = src[e];
        if (s >= lo && s < hi) atomicAdd(&deg[s], 1);
    }
}

// --- 3-phase exclusive scan of deg[N] -> rowptr[N+1] (+ cursor copy) ---
__global__ __launch_bounds__(SCAN_BS) void scan1_kernel(const int* __restrict__ deg,
                                                        int* __restrict__ chunkScan,
                                                        int* __restrict__ blockSums, int N) {
    __shared__ int tmp[SCAN_BS];
    int gid = blockIdx.x * SCAN_BS + threadIdx.x;
    int v = (gid < N) ? deg[gid] : 0;
    tmp[threadIdx.x] = v;
    __syncthreads();
    for (int off = 1; off < SCAN_BS; off <<= 1) {
        int add = (threadIdx.x >= off) ? tmp[threadIdx.x - off] : 0;
        __syncthreads();
        tmp[threadIdx.x] += add;
        __syncthreads();
    }
    if (gid < N) chunkScan[gid] = tmp[threadIdx.x] - v;
    if (threadIdx.x == SCAN_BS - 1) blockSums[blockIdx.x] = tmp[threadIdx.x];
}

__global__ __launch_bounds__(SCAN_BS) void scan2_kernel(int* __restrict__ blockSums, int nb) {
    __shared__ int tmp[SCAN_BS];
    int v = (threadIdx.x < nb) ? blockSums[threadIdx.x] : 0;
    tmp[threadIdx.x] = v;
    __syncthreads();
    for (int off = 1; off < SCAN_BS; off <<= 1) {
        int add = (threadIdx.x >= off) ? tmp[threadIdx.x - off] : 0;
        __syncthreads();
        tmp[threadIdx.x] += add;
        __syncthreads();
    }
    if (threadIdx.x < nb) blockSums[threadIdx.x] = tmp[threadIdx.x] - v;
}

__global__ void scan3_kernel(const int* __restrict__ chunkScan, const int* __restrict__ blockSums,
                             int* __restrict__ rowptr, int* __restrict__ cursor, int N, int E) {
    int gid = blockIdx.x * blockDim.x + threadIdx.x;
    if (gid < N) {
        int v = chunkScan[gid] + blockSums[gid / SCAN_BS];
        rowptr[gid] = v;
        cursor[gid] = v;
    }
    if (gid == 0) rowptr[N] = E;
}

// --- Partitioned CSR column fill (u16) ---
__global__ __launch_bounds__(256) void build_col_part(const int* __restrict__ src,
                                                      const int* __restrict__ dst,
                                                      int* __restrict__ cursor,
                                                      unsigned short* __restrict__ col,
                                                      int E, int N) {
    int g    = blockIdx.x & (NXCD - 1);
    int bpg  = blockIdx.x >> 3;
    int nbpg = gridDim.x >> 3;
    int chunk = (N + NXCD - 1) / NXCD;
    int lo = g * chunk;
    int hi = min(N, lo + chunk);
    for (int e = bpg * 256 + threadIdx.x; e < E; e += nbpg * 256) {
        int s = src[e];
        if (s >= lo && s < hi) {
            int pos = atomicAdd(&cursor[s], 1);
            col[pos] = (unsigned short)dst[e];
        }
    }
}

// One wave per node, lane = feature dim. 8-deep unroll for MLP.
__global__ __launch_bounds__(256) void gather_mean_kernel(const float* __restrict__ H,
                                                          const int* __restrict__ rowptr,
                                                          const unsigned short* __restrict__ col,
                                                          float* __restrict__ out, int N) {
    int node = blockIdx.x * 4 + (threadIdx.x >> 6);
    int lane = threadIdx.x & 63;
    if (node >= N) return;
    int beg = rowptr[node];
    int end = rowptr[node + 1];
    float acc = 0.f;
    int e = beg;
    for (; e + 8 <= end; e += 8) {               // 8 independent row loads in flight
        int t0 = col[e + 0], t1 = col[e + 1], t2 = col[e + 2], t3 = col[e + 3];
        int t4 = col[e + 4], t5 = col[e + 5], t6 = col[e + 6], t7 = col[e + 7];
        float v0 = H[(size_t)t0 * 64 + lane];
        float v1 = H[(size_t)t1 * 64 + lane];
        float v2 = H[(size_t)t2 * 64 + lane];
        float v3 = H[(size_t)t3 * 64 + lane];
        float v4 = H[(size_t)t4 * 64 + lane];
        float v5 = H[(size_t)t5 * 64 + lane];
        float v6 = H[(size_t)t6 * 64 + lane];
        float v7 = H[(size_t)t7 * 64 + lane];
        acc += (((v0 + v1) + (v2 + v3)) + ((v4 + v5) + (v6 + v7)));
    }
    for (; e + 2 <= end; e += 2) {
        int t0 = col[e + 0], t1 = col[e + 1];
        float v0 = H[(size_t)t0 * 64 + lane];
        float v1 = H[(size_t)t1 * 64 + lane];
        acc += (v0 + v1);
    }
    for (; e < end; ++e) acc += H[(size_t)col[e] * 64 + lane];
    float inv = (end > beg) ? 1.f / (float)(end - beg) : 0.f;
    out[(size_t)node * 64 + lane] = acc * inv;
}

// Y[n x 64] = (optional relu)(X[n x 64]) @ W + b. 256 thr, 32 rows/block.
template <bool RELU_IN>
__global__ __launch_bounds__(256) void gemm_fast(const float* __restrict__ X,
                                                 const float* __restrict__ W,
                                                 const float* __restrict__ b,
                                                 float* __restrict__ Y, int n) {
    __shared__ float xs[32][64];
    const int tid  = threadIdx.x;
    const int lane = tid & 63;
    const int wv   = tid >> 6;
    const int row0 = blockIdx.x * 32;

    for (int i = tid; i < 32 * 64; i += 256) {
        int rr = row0 + (i >> 6);
        float v = (rr < n) ? X[(size_t)row0 * 64 + i] : 0.f;
        if (RELU_IN) v = fmaxf(v, 0.f);
        xs[i >> 6][i & 63] = v;
    }
    float w[64];
#pragma unroll
    for (int k = 0; k < 64; ++k) w[k] = W[k * 64 + lane];
    const float bias = b[lane];
    __syncthreads();

#pragma unroll
    for (int r8 = 0; r8 < 8; ++r8) {
        const int r = wv * 8 + r8;
        float a0 = 0.f, a1 = 0.f, a2 = 0.f, a3 = 0.f;
#pragma unroll
        for (int k4 = 0; k4 < 16; ++k4) {
            float4 xv = *(const float4*)&xs[r][k4 * 4];
            a0 = fmaf(xv.x, w[4 * k4 + 0], a0);
            a1 = fmaf(xv.y, w[4 * k4 + 1], a1);
            a2 = fmaf(xv.z, w[4 * k4 + 2], a2);
            a3 = fmaf(xv.w, w[4 * k4 + 3], a3);
        }
        const int grow = row0 + r;
        if (grow < n) Y[(size_t)grow * 64 + lane] = bias + ((a0 + a1) + (a2 + a3));
    }
}

// out[row] = log_softmax( (relu(A2[row]) @ Wp1 + bp1) @ Wp2 + bp2 )
__global__ __launch_bounds__(256) void fused_post(const float* __restrict__ A2,
                                                  const float* __restrict__ Wp1,
                                                  const float* __restrict__ bp1,
                                                  const float* __restrict__ Wp2,
                                                  const float* __restrict__ bp2,
                                                  float* __restrict__ out, int n) {
    __shared__ float xs[32][64];
    __shared__ float ys[32][64];
    const int tid  = threadIdx.x;
    const int lane = tid & 63;
    const int wv   = tid >> 6;
    const int row0 = blockIdx.x * 32;

    // Stage relu(A2) rows.
    for (int i = tid; i < 32 * 64; i += 256) {
        int rr = row0 + (i >> 6);
        float v = (rr < n) ? A2[(size_t)row0 * 64 + i] : 0.f;
        xs[i >> 6][i & 63] = fmaxf(v, 0.f);
    }
    float w[64];
#pragma unroll
    for (int k = 0; k < 64; ++k) w[k] = Wp1[k * 64 + lane];
    const float bias1 = bp1[lane];
    __syncthreads();

    // GEMM1 -> ys
#pragma unroll
    for (int r8 = 0; r8 < 8; ++r8) {
        const int r = wv * 8 + r8;
        float a0 = 0.f, a1 = 0.f, a2 = 0.f, a3 = 0.f;
#pragma unroll
        for (int k4 = 0; k4 < 16; ++k4) {
            float4 xv = *(const float4*)&xs[r][k4 * 4];
            a0 = fmaf(xv.x, w[4 * k4 + 0], a0);
            a1 = fmaf(xv.y, w[4 * k4 + 1], a1);
            a2 = fmaf(xv.z, w[4 * k4 + 2], a2);
            a3 = fmaf(xv.w, w[4 * k4 + 3], a3);
        }
        ys[r][lane] = bias1 + ((a0 + a1) + (a2 + a3));
    }

    float w2[64];
#pragma unroll
    for (int k = 0; k < 64; ++k) w2[k] = (lane < 40) ? Wp2[k * 40 + lane] : 0.f;
    const float bias2 = (lane < 40) ? bp2[lane] : 0.f;
    __syncthreads();

    // GEMM2 + log_softmax per row.
#pragma unroll
    for (int r8 = 0; r8 < 8; ++r8) {
        const int r = wv * 8 + r8;
        float a0 = 0.f, a1 = 0.f, a2 = 0.f, a3 = 0.f;
#pragma unroll
        for (int k4 = 0; k4 < 16; ++k4) {
            float4 xv = *(const float4*)&ys[r][k4 * 4];
            a0 = fmaf(xv.x, w2[4 * k4 + 0], a0);
            a1 = fmaf(xv.y, w2[4 * k4 + 1], a1);
            a2 = fmaf(xv.z, w2[4 * k4 + 2], a2);
            a3 = fmaf(xv.w, w2[4 * k4 + 3], a3);
        }
        float v = bias2 + ((a0 + a1) + (a2 + a3));
        float vm = (lane < 40) ? v : -INFINITY;
        float m = vm;
#pragma unroll
        for (int o = 32; o; o >>= 1) m = fmaxf(m, __shfl_xor(m, o));
        float e = (lane < 40) ? expf(vm - m) : 0.f;
        float s = e;
#pragma unroll
        for (int o = 32; o; o >>= 1) s += __shfl_xor(s, o);
        float ls = logf(s);
        const int grow = row0 + r;
        if (grow < n && lane < 40) out[(size_t)grow * 40 + lane] = vm - m - ls;
    }
}

extern "C" void kernel_launch(void* const* d_in, const int* in_sizes, int n_in,
                              void* d_out, int out_size, void* d_ws, size_t ws_size,
                              hipStream_t stream) {
    const float* x   = (const float*)d_in[0];
    const int*   ei  = (const int*)d_in[1];
    const float* W1  = (const float*)d_in[2];
    const float* b1  = (const float*)d_in[3];
    const float* W2  = (const float*)d_in[4];
    const float* b2  = (const float*)d_in[5];
    const float* Wp1 = (const float*)d_in[6];
    const float* bp1 = (const float*)d_in[7];
    const float* Wp2 = (const float*)d_in[8];
    const float* bp2 = (const float*)d_in[9];
    float* out = (float*)d_out;

    const int N = in_sizes[0] / 64;
    const int E = in_sizes[1] / 2;
    const int* src = ei;
    const int* dst = ei + E;

    // Workspace layout
    char*  wsb = (char*)d_ws;
    size_t off = 0;
    auto alloc = [&](size_t bytes) { void* p = wsb + off; off += (bytes + 511) & ~(size_t)511; return p; };
    int*            deg       = (int*)alloc((size_t)N * 4);
    int*            rowptr    = (int*)alloc((size_t)(N + 1) * 4);
    int*            cursor    = (int*)alloc((size_t)N * 4);
    int*            chunkScan = (int*)alloc((size_t)N * 4);
    int*            blockSums = (int*)alloc((size_t)SCAN_BS * 4);
    unsigned short* col       = (unsigned short*)alloc((size_t)E * 2);
    float*          B1        = (float*)alloc((size_t)N * 64 * 4);
    float*          B2        = (float*)alloc((size_t)N * 64 * 4);
    (void)ws_size; (void)n_in; (void)out_size;

    const int scanBlocks = (N + SCAN_BS - 1) / SCAN_BS;
    const int nb32       = (N + 31) / 32;
    const int nodeBlocks = (N + 3) / 4;
    const int partBlocks = 1024;

    // --- Build CSR ---
    hipMemsetAsync(deg, 0, (size_t)N * 4, stream);
    count_deg_part<<<partBlocks, 256, 0, stream>>>(src, deg, E, N);
    scan1_kernel<<<scanBlocks, SCAN_BS, 0, stream>>>(deg, chunkScan, blockSums, N);
    scan2_kernel<<<1, SCAN_BS, 0, stream>>>(blockSums, scanBlocks);
    scan3_kernel<<<(N + 255) / 256, 256, 0, stream>>>(chunkScan, blockSums, rowptr, cursor, N, E);
    build_col_part<<<partBlocks, 256, 0, stream>>>(src, dst, cursor, col, E, N);

    // --- Pipeline ---
    gemm_fast<false><<<nb32, 256, 0, stream>>>(x, W1, b1, B1, N);                 // H1
    gather_mean_kernel<<<nodeBlocks, 256, 0, stream>>>(B1, rowptr, col, B2, N);   // A1
    gemm_fast<true><<<nb32, 256, 0, stream>>>(B2, W2, b2, B1, N);                 // H2 (relu in)
    gather_mean_kernel<<<nodeBlocks, 256, 0, stream>>>(B1, rowptr, col, B2, N);   // A2
    fused_post<<<nb32, 256, 0, stream>>>(B2, Wp1, bp1, Wp2, bp2, out, N);         // out
}

// Round 6
// 228.714 us; speedup vs baseline: 1.1734x; 1.0103x over previous
//
#include <hip/hip_runtime.h>
#include <hip/hip_fp16.h>
#include <cmath>

// GraphSAGE forward for MI355X (gfx950).
// R6: chunked-W GEMMs (fixes VGPR->scratch spill seen as VGPR_Count=52),
//     fp16 hidden states (halves the gather's L2/L3 stream), CSR unchanged.

#define SCAN_BS 512
#define NXCD 8

// --- Partitioned degree count ---
__global__ __launch_bounds__(256) void count_deg_part(const int* __restrict__ src,
                                                      int* __restrict__ deg, int E, int N) {
    int g    = blockIdx.x & (NXCD - 1);
    int bpg  = blockIdx.x >> 3;
    int nbpg = gridDim.x >> 3;
    int chunk = (N + NXCD - 1) / NXCD;
    int lo = g * chunk;
    int hi = min(N, lo + chunk);
    for (int e = bpg * 256 + threadIdx.x; e < E; e += nbpg * 256) {
        int s = src[e];
        if (s >= lo && s < hi) atomicAdd(&deg[s], 1);
    }
}

// --- 3-phase exclusive scan of deg[N] -> rowptr[N+1] (+ cursor copy) ---
__global__ __launch_bounds__(SCAN_BS) void scan1_kernel(const int* __restrict__ deg,
                                                        int* __restrict__ chunkScan,
                                                        int* __restrict__ blockSums, int N) {
    __shared__ int tmp[SCAN_BS];
    int gid = blockIdx.x * SCAN_BS + threadIdx.x;
    int v = (gid < N) ? deg[gid] : 0;
    tmp[threadIdx.x] = v;
    __syncthreads();
    for (int off = 1; off < SCAN_BS; off <<= 1) {
        int add = (threadIdx.x >= off) ? tmp[threadIdx.x - off] : 0;
        __syncthreads();
        tmp[threadIdx.x] += add;
        __syncthreads();
    }
    if (gid < N) chunkScan[gid] = tmp[threadIdx.x] - v;
    if (threadIdx.x == SCAN_BS - 1) blockSums[blockIdx.x] = tmp[threadIdx.x];
}

__global__ __launch_bounds__(SCAN_BS) void scan2_kernel(int* __restrict__ blockSums, int nb) {
    __shared__ int tmp[SCAN_BS];
    int v = (threadIdx.x < nb) ? blockSums[threadIdx.x] : 0;
    tmp[threadIdx.x] = v;
    __syncthreads();
    for (int off = 1; off < SCAN_BS; off <<= 1) {
        int add = (threadIdx.x >= off) ? tmp[threadIdx.x - off] : 0;
        __syncthreads();
        tmp[threadIdx.x] += add;
        __syncthreads();
    }
    if (threadIdx.x < nb) blockSums[threadIdx.x] = tmp[threadIdx.x] - v;
}

__global__ void scan3_kernel(const int* __restrict__ chunkScan, const int* __restrict__ blockSums,
                             int* __restrict__ rowptr, int* __restrict__ cursor, int N, int E) {
    int gid = blockIdx.x * blockDim.x + threadIdx.x;
    if (gid < N) {
        int v = chunkScan[gid] + blockSums[gid / SCAN_BS];
        rowptr[gid] = v;
        cursor[gid] = v;
    }
    if (gid == 0) rowptr[N] = E;
}

// --- Partitioned CSR column fill (u16) ---
__global__ __launch_bounds__(256) void build_col_part(const int* __restrict__ src,
                                                      const int* __restrict__ dst,
                                                      int* __restrict__ cursor,
                                                      unsigned short* __restrict__ col,
                                                      int E, int N) {
    int g    = blockIdx.x & (NXCD - 1);
    int bpg  = blockIdx.x >> 3;
    int nbpg = gridDim.x >> 3;
    int chunk = (N + NXCD - 1) / NXCD;
    int lo = g * chunk;
    int hi = min(N, lo + chunk);
    for (int e = bpg * 256 + threadIdx.x; e < E; e += nbpg * 256) {
        int s = src[e];
        if (s >= lo && s < hi) {
            int pos = atomicAdd(&cursor[s], 1);
            col[pos] = (unsigned short)dst[e];
        }
    }
}

// One wave per node, lane = feature dim. fp16 H, fp32 accumulate, 8-deep unroll.
__global__ __launch_bounds__(256) void gather_mean_h(const __half* __restrict__ H,
                                                     const int* __restrict__ rowptr,
                                                     const unsigned short* __restrict__ col,
                                                     float* __restrict__ out, int N) {
    int node = blockIdx.x * 4 + (threadIdx.x >> 6);
    int lane = threadIdx.x & 63;
    if (node >= N) return;
    int beg = rowptr[node];
    int end = rowptr[node + 1];
    float acc = 0.f;
    int e = beg;
    for (; e + 8 <= end; e += 8) {               // 8 independent row loads in flight
        int t0 = col[e + 0], t1 = col[e + 1], t2 = col[e + 2], t3 = col[e + 3];
        int t4 = col[e + 4], t5 = col[e + 5], t6 = col[e + 6], t7 = col[e + 7];
        float v0 = __half2float(H[(size_t)t0 * 64 + lane]);
        float v1 = __half2float(H[(size_t)t1 * 64 + lane]);
        float v2 = __half2float(H[(size_t)t2 * 64 + lane]);
        float v3 = __half2float(H[(size_t)t3 * 64 + lane]);
        float v4 = __half2float(H[(size_t)t4 * 64 + lane]);
        float v5 = __half2float(H[(size_t)t5 * 64 + lane]);
        float v6 = __half2float(H[(size_t)t6 * 64 + lane]);
        float v7 = __half2float(H[(size_t)t7 * 64 + lane]);
        acc += (((v0 + v1) + (v2 + v3)) + ((v4 + v5) + (v6 + v7)));
    }
    for (; e + 2 <= end; e += 2) {
        float v0 = __half2float(H[(size_t)col[e + 0] * 64 + lane]);
        float v1 = __half2float(H[(size_t)col[e + 1] * 64 + lane]);
        acc += (v0 + v1);
    }
    for (; e < end; ++e) acc += __half2float(H[(size_t)col[e] * 64 + lane]);
    float inv = (end > beg) ? 1.f / (float)(end - beg) : 0.f;
    out[(size_t)node * 64 + lane] = acc * inv;
}

// Chunked 16-FMA macro body: acc += xs[row][c*16 .. c*16+15] . wreg[0..15]
__device__ __forceinline__ float dot16(const float* xrow, const float* wreg, float a) {
    float4 x0 = *(const float4*)(xrow + 0);
    float4 x1 = *(const float4*)(xrow + 4);
    float4 x2 = *(const float4*)(xrow + 8);
    float4 x3 = *(const float4*)(xrow + 12);
    a = fmaf(x0.x, wreg[0], a);  a = fmaf(x0.y, wreg[1], a);
    a = fmaf(x0.z, wreg[2], a);  a = fmaf(x0.w, wreg[3], a);
    a = fmaf(x1.x, wreg[4], a);  a = fmaf(x1.y, wreg[5], a);
    a = fmaf(x1.z, wreg[6], a);  a = fmaf(x1.w, wreg[7], a);
    a = fmaf(x2.x, wreg[8], a);  a = fmaf(x2.y, wreg[9], a);
    a = fmaf(x2.z, wreg[10], a); a = fmaf(x2.w, wreg[11], a);
    a = fmaf(x3.x, wreg[12], a); a = fmaf(x3.y, wreg[13], a);
    a = fmaf(x3.z, wreg[14], a); a = fmaf(x3.w, wreg[15], a);
    return a;
}

// Y[n x 64] = (optional relu)(X[n x 64]) @ W + b.  Chunked W (no spill).
// HALF_OUT: store Y as fp16.
template <bool RELU_IN, bool HALF_OUT>
__global__ __launch_bounds__(256) void gemm64(const float* __restrict__ X,
                                              const float* __restrict__ W,
                                              const float* __restrict__ b,
                                              void* __restrict__ Yv, int n) {
    __shared__ float xs[32][64];
    const int tid  = threadIdx.x;
    const int lane = tid & 63;
    const int wid  = tid >> 6;
    const int row0 = blockIdx.x * 32;

    for (int i = tid; i < 32 * 64; i += 256) {
        int rr = row0 + (i >> 6);
        float v = (rr < n) ? X[(size_t)row0 * 64 + i] : 0.f;
        if (RELU_IN) v = fmaxf(v, 0.f);
        xs[i >> 6][i & 63] = v;
    }
    const float bias = b[lane];
    __syncthreads();

    float acc[8];
#pragma unroll
    for (int r = 0; r < 8; ++r) acc[r] = bias;

#pragma unroll 1
    for (int c = 0; c < 4; ++c) {
        float wreg[16];
#pragma unroll
        for (int j = 0; j < 16; ++j) wreg[j] = W[(c * 16 + j) * 64 + lane];
#pragma unroll
        for (int r = 0; r < 8; ++r)
            acc[r] = dot16(&xs[wid * 8 + r][c * 16], wreg, acc[r]);
    }

#pragma unroll
    for (int r = 0; r < 8; ++r) {
        const int grow = row0 + wid * 8 + r;
        if (grow < n) {
            if (HALF_OUT) ((__half*)Yv)[(size_t)grow * 64 + lane] = __float2half(acc[r]);
            else          ((float*)Yv)[(size_t)grow * 64 + lane] = acc[r];
        }
    }
}

// out[row] = log_softmax( (relu(A2[row]) @ Wp1 + bp1) @ Wp2 + bp2 ). Chunked W.
__global__ __launch_bounds__(256) void fused_post(const float* __restrict__ A2,
                                                  const float* __restrict__ Wp1,
                                                  const float* __restrict__ bp1,
                                                  const float* __restrict__ Wp2,
                                                  const float* __restrict__ bp2,
                                                  float* __restrict__ out, int n) {
    __shared__ float xs[32][64];
    __shared__ float ys[32][64];
    const int tid  = threadIdx.x;
    const int lane = tid & 63;
    const int wid  = tid >> 6;
    const int row0 = blockIdx.x * 32;

    for (int i = tid; i < 32 * 64; i += 256) {
        int rr = row0 + (i >> 6);
        float v = (rr < n) ? A2[(size_t)row0 * 64 + i] : 0.f;
        xs[i >> 6][i & 63] = fmaxf(v, 0.f);
    }
    const float bias1 = bp1[lane];
    __syncthreads();

    // GEMM1 (chunked) -> ys (each wave writes/reads only its own 8 rows).
    float acc[8];
#pragma unroll
    for (int r = 0; r < 8; ++r) acc[r] = bias1;
#pragma unroll 1
    for (int c = 0; c < 4; ++c) {
        float wreg[16];
#pragma unroll
        for (int j = 0; j < 16; ++j) wreg[j] = Wp1[(c * 16 + j) * 64 + lane];
#pragma unroll
        for (int r = 0; r < 8; ++r)
            acc[r] = dot16(&xs[wid * 8 + r][c * 16], wreg, acc[r]);
    }
#pragma unroll
    for (int r = 0; r < 8; ++r) ys[wid * 8 + r][lane] = acc[r];

    // GEMM2 (chunked, KOUT=40) + log_softmax. No barrier: wave-private rows.
    const float bias2 = (lane < 40) ? bp2[lane] : 0.f;
#pragma unroll
    for (int r = 0; r < 8; ++r) acc[r] = bias2;
#pragma unroll 1
    for (int c = 0; c < 4; ++c) {
        float wreg[16];
#pragma unroll
        for (int j = 0; j < 16; ++j)
            wreg[j] = (lane < 40) ? Wp2[(c * 16 + j) * 40 + lane] : 0.f;
#pragma unroll
        for (int r = 0; r < 8; ++r)
            acc[r] = dot16(&ys[wid * 8 + r][c * 16], wreg, acc[r]);
    }

#pragma unroll
    for (int r = 0; r < 8; ++r) {
        float vm = (lane < 40) ? acc[r] : -INFINITY;
        float m = vm;
#pragma unroll
        for (int o = 32; o; o >>= 1) m = fmaxf(m, __shfl_xor(m, o));
        float e = (lane < 40) ? expf(vm - m) : 0.f;
        float s = e;
#pragma unroll
        for (int o = 32; o; o >>= 1) s += __shfl_xor(s, o);
        float ls = logf(s);
        const int grow = row0 + wid * 8 + r;
        if (grow < n && lane < 40) out[(size_t)grow * 40 + lane] = vm - m - ls;
    }
}

extern "C" void kernel_launch(void* const* d_in, const int* in_sizes, int n_in,
                              void* d_out, int out_size, void* d_ws, size_t ws_size,
                              hipStream_t stream) {
    const float* x   = (const float*)d_in[0];
    const int*   ei  = (const int*)d_in[1];
    const float* W1  = (const float*)d_in[2];
    const float* b1  = (const float*)d_in[3];
    const float* W2  = (const float*)d_in[4];
    const float* b2  = (const float*)d_in[5];
    const float* Wp1 = (const float*)d_in[6];
    const float* bp1 = (const float*)d_in[7];
    const float* Wp2 = (const float*)d_in[8];
    const float* bp2 = (const float*)d_in[9];
    float* out = (float*)d_out;

    const int N = in_sizes[0] / 64;
    const int E = in_sizes[1] / 2;
    const int* src = ei;
    const int* dst = ei + E;

    // Workspace layout
    char*  wsb = (char*)d_ws;
    size_t off = 0;
    auto alloc = [&](size_t bytes) { void* p = wsb + off; off += (bytes + 511) & ~(size_t)511; return p; };
    int*            deg       = (int*)alloc((size_t)N * 4);
    int*            rowptr    = (int*)alloc((size_t)(N + 1) * 4);
    int*            cursor    = (int*)alloc((size_t)N * 4);
    int*            chunkScan = (int*)alloc((size_t)N * 4);
    int*            blockSums = (int*)alloc((size_t)SCAN_BS * 4);
    unsigned short* col       = (unsigned short*)alloc((size_t)E * 2);
    __half*         Hh        = (__half*)alloc((size_t)N * 64 * 2);   // H1 / H2 (fp16)
    float*          A         = (float*)alloc((size_t)N * 64 * 4);    // A1 / A2 (fp32)
    (void)ws_size; (void)n_in; (void)out_size;

    const int scanBlocks = (N + SCAN_BS - 1) / SCAN_BS;
    const int nb32       = (N + 31) / 32;
    const int nodeBlocks = (N + 3) / 4;
    const int partBlocks = 1024;

    // --- Build CSR ---
    hipMemsetAsync(deg, 0, (size_t)N * 4, stream);
    count_deg_part<<<partBlocks, 256, 0, stream>>>(src, deg, E, N);
    scan1_kernel<<<scanBlocks, SCAN_BS, 0, stream>>>(deg, chunkScan, blockSums, N);
    scan2_kernel<<<1, SCAN_BS, 0, stream>>>(blockSums, scanBlocks);
    scan3_kernel<<<(N + 255) / 256, 256, 0, stream>>>(chunkScan, blockSums, rowptr, cursor, N, E);
    build_col_part<<<partBlocks, 256, 0, stream>>>(src, dst, cursor, col, E, N);

    // --- Pipeline ---
    gemm64<false, true><<<nb32, 256, 0, stream>>>(x, W1, b1, Hh, N);              // H1 (fp16)
    gather_mean_h<<<nodeBlocks, 256, 0, stream>>>(Hh, rowptr, col, A, N);         // A1 (fp32)
    gemm64<true, true><<<nb32, 256, 0, stream>>>(A, W2, b2, Hh, N);               // H2 (fp16, relu in)
    gather_mean_h<<<nodeBlocks, 256, 0, stream>>>(Hh, rowptr, col, A, N);         // A2 (fp32)
    fused_post<<<nb32, 256, 0, stream>>>(A, Wp1, bp1, Wp2, bp2, out, N);          // out
}